// Round 1
// baseline (1284.243 us; speedup 1.0000x reference)
//
#include <hip/hip_runtime.h>
#include <cfloat>
#include <cstdint>

// Problem constants
#define NROWS 131072
#define DIMD  128
#define KCODE 1024
#define MARGIN 0.02f   // fast-path gap below which we re-resolve argmin in fp64

// ---- workspace layout (bytes); total ~2.02 MB ----
#define WS_REFINE_CNT 0         // int
#define WS_LOSS       8         // double
#define WS_COUNTS     16        // int[1024]
#define WS_OFFSETS    4112      // int[1024]
#define WS_CURSOR     8208      // int[1024]
#define WS_E2         12304     // float[1024]
#define WS_ET         16400     // float[K*D] = 512 KB
#define WS_IDX        540688    // int[N]
#define WS_ROWLIST    1064976   // int[N]
#define WS_REFINE     1589264   // int[N]

// ---- output offsets (in floats), reference return order ----
#define OUT_QST  ((size_t)0)
#define OUT_EMB  ((size_t)NROWS * DIMD)
#define OUT_CNT  (OUT_EMB + (size_t)DIMD * KCODE)
#define OUT_ES   (OUT_CNT + KCODE)
#define OUT_LOSS (OUT_ES + (size_t)DIMD * KCODE)

// ============================================================
// e2[k] = sum_d E[d][k]^2   (coalesced over k)
__global__ void vq_prep_e2(const float* __restrict__ E, float* __restrict__ e2) {
    int k = blockIdx.x * 256 + threadIdx.x;
    if (k >= KCODE) return;
    float s = 0.f;
    for (int d = 0; d < DIMD; ++d) {
        float v = E[(size_t)d * KCODE + k];
        s = fmaf(v, v, s);
    }
    e2[k] = s;
}

// ET[k][d] = E[d][k]  (LDS-tiled transpose)
__global__ void vq_transpose(const float* __restrict__ E, float* __restrict__ ET) {
    __shared__ float tile[32][33];
    int kb = blockIdx.x * 32, db = blockIdx.y * 32;
    int tx = threadIdx.x, ty = threadIdx.y;  // 32 x 8
    #pragma unroll
    for (int j = 0; j < 32; j += 8)
        tile[ty + j][tx] = E[(size_t)(db + ty + j) * KCODE + kb + tx];
    __syncthreads();
    #pragma unroll
    for (int j = 0; j < 32; j += 8)
        ET[(size_t)(kb + ty + j) * DIMD + db + tx] = tile[tx][ty + j];
}

// ============================================================
// Main kernel: per-row argmin_k ( ||e_k||^2 - 2 x.e_k ) via register-tiled
// fp32 GEMM. 128x128 row/col tile, 8x8 micro-tile, XOR-swizzled transposed
// A in LDS (conflict-free b128 reads), running (min1,min2) per row.
// Rows with gap <= MARGIN are pushed to a refine list (fp64 recheck).
__global__ __launch_bounds__(256) void vq_argmin_gemm(
        const float* __restrict__ x, const float* __restrict__ E,
        const float* __restrict__ e2, int* __restrict__ idx,
        int* __restrict__ refine_rows, int* __restrict__ refine_cnt) {
    __shared__ float As[128 * 128];  // As[d*128 + (row ^ sw(d))], sw(d)=((d>>2)&3)<<3
    __shared__ float Bs[128 * 128];  // Bs[d*128 + c]
    const int tid = threadIdx.x;
    const int tx = tid & 15, ty = tid >> 4;
    const size_t row0 = (size_t)blockIdx.x * 128;

    // Stage A (once): coalesced global float4 loads, swizzled scatter to LDS
    #pragma unroll
    for (int p = 0; p < 16; ++p) {
        int lin = (tid + p * 256) * 4;    // 0..16380
        int r = lin >> 7;                  // row in tile
        int d = lin & 127;                 // d (multiple of 4)
        float4 v = *(const float4*)(x + (row0 + r) * DIMD + d);
        int sw = ((d >> 2) & 3) << 3;
        int rs = r ^ sw;
        As[(d + 0) * 128 + rs] = v.x;
        As[(d + 1) * 128 + rs] = v.y;
        As[(d + 2) * 128 + rs] = v.z;
        As[(d + 3) * 128 + rs] = v.w;
    }

    float m1[8], m2[8];
    int i1[8];
    #pragma unroll
    for (int i = 0; i < 8; ++i) { m1[i] = FLT_MAX; m2[i] = FLT_MAX; i1[i] = 0; }

    for (int ch = 0; ch < 8; ++ch) {
        __syncthreads();  // As visible (iter 0) / previous Bs consumers done
        #pragma unroll
        for (int p = 0; p < 16; ++p) {
            int lin = (tid + p * 256) * 4;
            int d = lin >> 7, c = lin & 127;
            float4 v = *(const float4*)(E + (size_t)d * KCODE + ch * 128 + c);
            *(float4*)&Bs[d * 128 + c] = v;
        }
        __syncthreads();

        float acc[8][8];
        #pragma unroll
        for (int i = 0; i < 8; ++i)
            #pragma unroll
            for (int j = 0; j < 8; ++j) acc[i][j] = 0.f;

        #pragma unroll 4
        for (int d = 0; d < 128; ++d) {
            float a[8], b[8];
            int sw = ((d >> 2) & 3) << 3;
            int abase = d * 128 + ((ty * 8) ^ sw);
            *(float4*)&a[0] = *(const float4*)&As[abase];
            *(float4*)&a[4] = *(const float4*)&As[abase + 4];
            int bbase = d * 128 + tx * 8;
            *(float4*)&b[0] = *(const float4*)&Bs[bbase];
            *(float4*)&b[4] = *(const float4*)&Bs[bbase + 4];
            #pragma unroll
            for (int i = 0; i < 8; ++i)
                #pragma unroll
                for (int j = 0; j < 8; ++j)
                    acc[i][j] = fmaf(a[i], b[j], acc[i][j]);
        }

        // Finalize chunk: score = e2[col] - 2*sim, update running (min1,min2)
        float e2v[8];
        *(float4*)&e2v[0] = *(const float4*)(e2 + ch * 128 + tx * 8);
        *(float4*)&e2v[4] = *(const float4*)(e2 + ch * 128 + tx * 8 + 4);
        #pragma unroll
        for (int j = 0; j < 8; ++j) {
            int col = ch * 128 + tx * 8 + j;
            #pragma unroll
            for (int i = 0; i < 8; ++i) {
                float s = fmaf(-2.0f, acc[i][j], e2v[j]);
                if (s < m1[i]) { m2[i] = m1[i]; m1[i] = s; i1[i] = col; }
                else if (s < m2[i]) { m2[i] = s; }
            }
        }
    }

    // Cross-thread merge (16 tx-threads share each row) via LDS (reuse As)
    __syncthreads();
    float* M1 = As;
    float* M2 = As + 2048;
    int*   I1 = (int*)(As + 4096);
    #pragma unroll
    for (int i = 0; i < 8; ++i) {
        int r = ty * 8 + i;
        M1[r * 16 + tx] = m1[i];
        M2[r * 16 + tx] = m2[i];
        I1[r * 16 + tx] = i1[i];
    }
    __syncthreads();
    if (tid < 128) {
        float bm1 = FLT_MAX, bm2 = FLT_MAX;
        int bi = 0;
        for (int t = 0; t < 16; ++t) {
            float c1 = M1[tid * 16 + t];
            float c2 = M2[tid * 16 + t];
            int   ci = I1[tid * 16 + t];
            if (c1 < bm1) {
                bm2 = fminf(bm1, c2);
                bm1 = c1; bi = ci;
            } else {
                if (c1 == bm1 && ci < bi) bi = ci;  // first-occurrence tie-break
                bm2 = fminf(bm2, c1);
            }
        }
        int n = (int)row0 + tid;
        idx[n] = bi;
        if (!(bm2 - bm1 > MARGIN)) {  // ambiguous -> exact fp64 recheck
            int pos = atomicAdd(refine_cnt, 1);
            refine_rows[pos] = n;
        }
    }
}

// ============================================================
// fp64 exact re-resolution of ambiguous rows (true argmin, first-index ties)
__global__ void vq_refine(const float* __restrict__ x, const float* __restrict__ E,
                          const int* __restrict__ refine_rows,
                          const int* __restrict__ refine_cnt, int* __restrict__ idx) {
    __shared__ float xs[DIMD];
    __shared__ double rm[256];
    __shared__ int ri[256];
    int cnt = *refine_cnt;
    for (int w = blockIdx.x; w < cnt; w += gridDim.x) {
        int n = refine_rows[w];
        __syncthreads();
        if (threadIdx.x < DIMD) xs[threadIdx.x] = x[(size_t)n * DIMD + threadIdx.x];
        __syncthreads();
        double best = DBL_MAX;
        int bi = 0;
        for (int k = threadIdx.x; k < KCODE; k += 256) {  // k ascending per thread
            double s = 0.0;
            for (int d = 0; d < DIMD; ++d) {
                double diff = (double)xs[d] - (double)E[(size_t)d * KCODE + k];
                s = fma(diff, diff, s);
            }
            if (s < best) { best = s; bi = k; }
        }
        rm[threadIdx.x] = best; ri[threadIdx.x] = bi;
        __syncthreads();
        for (int off = 128; off > 0; off >>= 1) {
            if (threadIdx.x < off) {
                double o = rm[threadIdx.x + off];
                int oi = ri[threadIdx.x + off];
                if (o < rm[threadIdx.x] ||
                    (o == rm[threadIdx.x] && oi < ri[threadIdx.x])) {
                    rm[threadIdx.x] = o; ri[threadIdx.x] = oi;
                }
            }
            __syncthreads();
        }
        if (threadIdx.x == 0) idx[n] = ri[0];
    }
}

// ============================================================
__global__ void vq_hist(const int* __restrict__ idx, int* __restrict__ counts) {
    int n = blockIdx.x * 256 + threadIdx.x;
    if (n < NROWS) atomicAdd(&counts[idx[n]], 1);
}

__global__ void vq_scan(const int* __restrict__ counts, int* __restrict__ offsets,
                        int* __restrict__ cursor) {
    __shared__ int s[KCODE];
    int t = threadIdx.x;
    int c = counts[t];
    s[t] = c;
    __syncthreads();
    for (int off = 1; off < KCODE; off <<= 1) {
        int v = (t >= off) ? s[t - off] : 0;
        __syncthreads();
        s[t] += v;
        __syncthreads();
    }
    int excl = s[t] - c;
    offsets[t] = excl;
    cursor[t] = excl;
}

__global__ void vq_fill(const int* __restrict__ idx, int* __restrict__ cursor,
                        int* __restrict__ rowlist) {
    int n = blockIdx.x * 256 + threadIdx.x;
    if (n < NROWS) {
        int k = idx[n];
        int pos = atomicAdd(&cursor[k], 1);
        rowlist[pos] = n;
    }
}

// One block per code: segment-sum of x rows (no atomics) + EMA outputs
__global__ void vq_code_update(const float* __restrict__ x,
                               const int* __restrict__ rowlist,
                               const int* __restrict__ offsets,
                               const int* __restrict__ counts,
                               const float* __restrict__ ema_count,
                               const float* __restrict__ es,
                               float* __restrict__ out) {
    __shared__ int rl[128];
    int k = blockIdx.x;
    int d = threadIdx.x;  // 128 threads
    int start = offsets[k];
    int len = counts[k];
    float s = 0.f;
    for (int base = 0; base < len; base += 128) {
        __syncthreads();
        int m = min(128, len - base);
        if (d < m) rl[d] = rowlist[start + base + d];
        __syncthreads();
        for (int j = 0; j < m; ++j)
            s += x[(size_t)rl[j] * DIMD + d];
    }
    float ecn = fmaf(0.85f, (float)len, 0.15f * ema_count[k]);
    float esn = fmaf(0.85f, s, 0.15f * es[(size_t)d * KCODE + k]);
    out[OUT_ES + (size_t)d * KCODE + k] = esn;
    out[OUT_EMB + (size_t)d * KCODE + k] = esn / fmaxf(ecn, 1e-5f);
    if (d == 0) out[OUT_CNT + k] = ecn;
}

// q_st = x + (quantized - x) (replicating reference fp32 rounding) + loss
__global__ void vq_quantize_loss(const float* __restrict__ x,
                                 const float* __restrict__ ET,
                                 const int* __restrict__ idx,
                                 float* __restrict__ out,
                                 double* __restrict__ loss) {
    size_t gid = (size_t)blockIdx.x * 256 + threadIdx.x;
    size_t base = gid * 4;
    int n = (int)(base >> 7);
    int d = (int)(base & 127);
    int k = idx[n];
    float4 xv = *(const float4*)(x + base);
    float4 qv = *(const float4*)(ET + (size_t)k * DIMD + d);
    float t0 = qv.x - xv.x, t1 = qv.y - xv.y, t2 = qv.z - xv.z, t3 = qv.w - xv.w;
    float4 o;
    o.x = xv.x + t0; o.y = xv.y + t1; o.z = xv.z + t2; o.w = xv.w + t3;
    *(float4*)(out + OUT_QST + base) = o;
    float partial = t0 * t0 + t1 * t1 + t2 * t2 + t3 * t3;
    // block reduce
    #pragma unroll
    for (int off = 32; off > 0; off >>= 1)
        partial += __shfl_down(partial, off);
    __shared__ float wsum[4];
    int wave = threadIdx.x >> 6;
    if ((threadIdx.x & 63) == 0) wsum[wave] = partial;
    __syncthreads();
    if (threadIdx.x == 0)
        atomicAdd(loss, (double)(wsum[0] + wsum[1] + wsum[2] + wsum[3]));
}

__global__ void vq_finalize_loss(const double* __restrict__ loss, float* __restrict__ out) {
    out[OUT_LOSS] = (float)(*loss / ((double)NROWS * (double)DIMD));  // BETA = 1
}

// ============================================================
extern "C" void kernel_launch(void* const* d_in, const int* in_sizes, int n_in,
                              void* d_out, int out_size, void* d_ws, size_t ws_size,
                              hipStream_t stream) {
    const float* x   = (const float*)d_in[0];
    const float* E   = (const float*)d_in[1];
    const float* emc = (const float*)d_in[2];
    const float* es  = (const float*)d_in[3];
    float* out = (float*)d_out;
    char* ws = (char*)d_ws;

    int*    refine_cnt  = (int*)(ws + WS_REFINE_CNT);
    double* loss        = (double*)(ws + WS_LOSS);
    int*    counts      = (int*)(ws + WS_COUNTS);
    int*    offsets     = (int*)(ws + WS_OFFSETS);
    int*    cursor      = (int*)(ws + WS_CURSOR);
    float*  e2          = (float*)(ws + WS_E2);
    float*  ET          = (float*)(ws + WS_ET);
    int*    idx         = (int*)(ws + WS_IDX);
    int*    rowlist     = (int*)(ws + WS_ROWLIST);
    int*    refine_rows = (int*)(ws + WS_REFINE);

    // zero refine counter, loss accumulator, counts
    hipMemsetAsync(ws, 0, WS_OFFSETS, stream);

    vq_prep_e2<<<4, 256, 0, stream>>>(E, e2);
    vq_transpose<<<dim3(KCODE / 32, DIMD / 32), dim3(32, 8), 0, stream>>>(E, ET);
    vq_argmin_gemm<<<NROWS / 128, 256, 0, stream>>>(x, E, e2, idx, refine_rows, refine_cnt);
    vq_refine<<<256, 256, 0, stream>>>(x, E, refine_rows, refine_cnt, idx);
    vq_hist<<<NROWS / 256, 256, 0, stream>>>(idx, counts);
    vq_scan<<<1, KCODE, 0, stream>>>(counts, offsets, cursor);
    vq_fill<<<NROWS / 256, 256, 0, stream>>>(idx, cursor, rowlist);
    vq_code_update<<<KCODE, 128, 0, stream>>>(x, rowlist, offsets, counts, emc, es, out);
    vq_quantize_loss<<<(NROWS * (size_t)DIMD) / (256 * 4), 256, 0, stream>>>(x, ET, idx, out, loss);
    vq_finalize_loss<<<1, 1, 0, stream>>>(loss, out);
}

// Round 2
// 582.839 us; speedup vs baseline: 2.2034x; 2.2034x over previous
//
#include <hip/hip_runtime.h>
#include <cfloat>
#include <cstdint>

// Problem constants
#define NROWS 131072
#define DIMD  128
#define KCODE 1024
#define MARGIN 0.02f   // fast-path gap below which we re-resolve argmin in fp64

typedef __attribute__((ext_vector_type(8))) short short8;  // 8 bf16 = 4 VGPRs
typedef __attribute__((ext_vector_type(4))) float f32x4;

union U4S8 { uint4 u; short8 s; };

// ---- workspace layout (bytes); total ~3.2 MB ----
#define WS_REFINE_CNT 0         // int
#define WS_LOSS       8         // double
#define WS_COUNTS     16        // int[1024]
#define WS_SUMS       4608      // float[K*D] = 512 KB (layout [k][d])
#define WS_ZERO_BYTES 528896    // memset [0, WS_ZERO_BYTES)
#define WS_OFFSETS    528896    // int[1024]
#define WS_CURSOR     532992    // int[1024]
#define WS_E2         537088    // float[1024]
#define WS_ET         541184    // float[K*D] (ET[k][d])
#define WS_BHI        1065472   // uint4[16384] = 256 KB (B hi fragments)
#define WS_BLO        1327616   // uint4[16384]
#define WS_IDX        1589760   // int[N]
#define WS_ROWLIST    2114048   // int[N]
#define WS_REFINE     2638336   // int[N]

// ---- output offsets (in floats), reference return order ----
#define OUT_QST  ((size_t)0)
#define OUT_EMB  ((size_t)NROWS * DIMD)
#define OUT_CNT  (OUT_EMB + (size_t)DIMD * KCODE)
#define OUT_ES   (OUT_CNT + KCODE)
#define OUT_LOSS (OUT_ES + (size_t)DIMD * KCODE)

// bf16 round-to-nearest-even of a float, as uint16 payload
__device__ __forceinline__ unsigned bf16rne(float f) {
    union { float f; unsigned u; } c; c.f = f;
    return (c.u + 0x7fffu + ((c.u >> 16) & 1u)) >> 16;
}
__device__ __forceinline__ float bf16back(unsigned h) {
    union { unsigned u; float f; } c; c.u = h << 16;
    return c.f;
}

// ============================================================
// e2[k] = sum_d E[d][k]^2   (coalesced over k)
__global__ void vq_prep_e2(const float* __restrict__ E, float* __restrict__ e2) {
    int k = blockIdx.x * 256 + threadIdx.x;
    if (k >= KCODE) return;
    float s = 0.f;
    for (int d = 0; d < DIMD; ++d) {
        float v = E[(size_t)d * KCODE + k];
        s = fmaf(v, v, s);
    }
    e2[k] = s;
}

// ET[k][d] = E[d][k]  (LDS-tiled transpose)
__global__ void vq_transpose(const float* __restrict__ E, float* __restrict__ ET) {
    __shared__ float tile[32][33];
    int kb = blockIdx.x * 32, db = blockIdx.y * 32;
    int tx = threadIdx.x, ty = threadIdx.y;  // 32 x 8
    #pragma unroll
    for (int j = 0; j < 32; j += 8)
        tile[ty + j][tx] = E[(size_t)(db + ty + j) * KCODE + kb + tx];
    __syncthreads();
    #pragma unroll
    for (int j = 0; j < 32; j += 8)
        ET[(size_t)(kb + ty + j) * DIMD + db + tx] = tile[tx][ty + j];
}

// Pack E into MFMA B-fragment order, split hi/lo bf16.
// Fragment fi = (NB*4 + t)*64 + lane; lane holds B[k = t*32 + (lane>>4)*8 + j]
// [n = NB*16 + (lane&15)], j = 0..7, value = E[k][n] (k is the d-dimension).
__global__ void vq_prep_bfrag(const float* __restrict__ E,
                              uint4* __restrict__ Bhi, uint4* __restrict__ Blo) {
    int gid = blockIdx.x * 256 + threadIdx.x;   // 0..16383 == fi
    int l = gid & 63;
    int t = (gid >> 6) & 3;
    int NB = gid >> 8;
    int n = NB * 16 + (l & 15);
    int k0 = t * 32 + (l >> 4) * 8;
    unsigned hu[8], lu[8];
    #pragma unroll
    for (int j = 0; j < 8; ++j) {
        float v = E[(size_t)(k0 + j) * KCODE + n];
        unsigned h = bf16rne(v);
        hu[j] = h;
        lu[j] = bf16rne(v - bf16back(h));
    }
    Bhi[gid] = make_uint4(hu[0] | (hu[1] << 16), hu[2] | (hu[3] << 16),
                          hu[4] | (hu[5] << 16), hu[6] | (hu[7] << 16));
    Blo[gid] = make_uint4(lu[0] | (lu[1] << 16), lu[2] | (lu[3] << 16),
                          lu[4] | (lu[5] << 16), lu[6] | (lu[7] << 16));
}

// ============================================================
// async global->LDS 16B copy
__device__ __forceinline__ void async16(const uint4* g, uint4* l) {
    __builtin_amdgcn_global_load_lds(
        (const __attribute__((address_space(1))) void*)g,
        (__attribute__((address_space(3))) void*)l, 16, 0, 0);
}

// Stage one 64-code chunk (hi 16KB + lo 16KB) into LDS, wave-partitioned.
__device__ __forceinline__ void stage_chunk(const uint4* __restrict__ Bhi,
                                            const uint4* __restrict__ Blo,
                                            int c, uint4* buf, int w, int l) {
    const uint4* src = (w < 2) ? (Bhi + c * 1024 + w * 512 + l)
                               : (Blo + c * 1024 + (w - 2) * 512 + l);
    uint4* dst = buf + w * 512 + l;
    #pragma unroll
    for (int j = 0; j < 8; ++j)
        async16(src + j * 64, dst + j * 64);
}

// Main kernel: per-row argmin_k ( ||e_k||^2 - 2 x.e_k ) via bf16 hi/lo split
// MFMA (3 passes: hh + lh + hl; residual ~1e-3 << MARGIN). 256 rows/block,
// 4 waves x 64 rows (4 m-tiles of 16). B double-buffered in LDS via
// global_load_lds; A fragments built in-register via per-wave swizzled LDS
// scratch. Running (min1,min2,idx) per row in MFMA C-layout, shfl_xor merge.
__global__ __launch_bounds__(256, 2) void vq_argmin_mfma(
        const float* __restrict__ x, const uint4* __restrict__ Bhi,
        const uint4* __restrict__ Blo, const float* __restrict__ e2,
        int* __restrict__ idx, int* __restrict__ counts,
        int* __restrict__ refine_rows, int* __restrict__ refine_cnt) {

    __shared__ uint4 Bs[2][2048];   // 2 x 32 KB

    const int tid = threadIdx.x;
    const int w = tid >> 6, l = tid & 63;
    const int m = l & 15, q = l >> 4;
    const int row0 = blockIdx.x * 256;
    const int rw = row0 + w * 64;

    // ---------- A-phase: build hi/lo A-fragments in registers ----------
    short8 ah[4][4], al[4][4];      // [m-tile][k-tile]
    float4* sc4 = ((float4*)&Bs[1][0]) + w * 512;   // 8 KB private scratch/wave

    #pragma unroll
    for (int mt = 0; mt < 4; ++mt) {
        int rm = rw + mt * 16;
        #pragma unroll
        for (int i = 0; i < 8; ++i) {
            int f = i * 64 + l, r = f >> 5, g = f & 31;
            float4 v = ((const float4*)x)[(size_t)(rm + r) * 32 + g];
            sc4[r * 32 + (g ^ ((r & 7) << 2))] = v;   // XOR swizzle vs banks
        }
        __builtin_amdgcn_s_waitcnt(0);   // in-wave LDS write->read ordering
        int sw = (m & 7) << 2;
        #pragma unroll
        for (int t = 0; t < 4; ++t) {
            int g0 = t * 8 + q * 2;
            float4 va = sc4[m * 32 + (g0 ^ sw)];
            float4 vb = sc4[m * 32 + ((g0 + 1) ^ sw)];
            float f8[8] = {va.x, va.y, va.z, va.w, vb.x, vb.y, vb.z, vb.w};
            unsigned hu[8], lu[8];
            #pragma unroll
            for (int j = 0; j < 8; ++j) {
                unsigned h = bf16rne(f8[j]);
                hu[j] = h;
                lu[j] = bf16rne(f8[j] - bf16back(h));
            }
            U4S8 ch, cl;
            ch.u = make_uint4(hu[0] | (hu[1] << 16), hu[2] | (hu[3] << 16),
                              hu[4] | (hu[5] << 16), hu[6] | (hu[7] << 16));
            cl.u = make_uint4(lu[0] | (lu[1] << 16), lu[2] | (lu[3] << 16),
                              lu[4] | (lu[5] << 16), lu[6] | (lu[7] << 16));
            ah[mt][t] = ch.s;
            al[mt][t] = cl.s;
        }
    }

    float m1[4][4], m2[4][4];
    int i1[4][4];
    #pragma unroll
    for (int a = 0; a < 4; ++a)
        #pragma unroll
        for (int r = 0; r < 4; ++r) { m1[a][r] = FLT_MAX; m2[a][r] = FLT_MAX; i1[a][r] = 0; }

    // ---------- K-loop over 16 chunks of 64 codes ----------
    stage_chunk(Bhi, Blo, 0, &Bs[0][0], w, l);
    __syncthreads();   // also covers: all waves done with scratch (Bs[1])

    for (int c = 0; c < 16; ++c) {
        if (c < 15) stage_chunk(Bhi, Blo, c + 1, &Bs[(c + 1) & 1][0], w, l);
        uint4* buf = &Bs[c & 1][0];
        #pragma unroll
        for (int b = 0; b < 4; ++b) {
            int nb = c * 4 + b;
            f32x4 acc[4];
            #pragma unroll
            for (int mt = 0; mt < 4; ++mt) acc[mt] = (f32x4){0.f, 0.f, 0.f, 0.f};
            #pragma unroll
            for (int t = 0; t < 4; ++t) {
                U4S8 bh, bl;
                bh.u = buf[(b * 4 + t) * 64 + l];
                bl.u = buf[1024 + (b * 4 + t) * 64 + l];
                #pragma unroll
                for (int mt = 0; mt < 4; ++mt) {
                    acc[mt] = __builtin_amdgcn_mfma_f32_16x16x32_bf16(ah[mt][t], bh.s, acc[mt], 0, 0, 0);
                    acc[mt] = __builtin_amdgcn_mfma_f32_16x16x32_bf16(al[mt][t], bh.s, acc[mt], 0, 0, 0);
                    acc[mt] = __builtin_amdgcn_mfma_f32_16x16x32_bf16(ah[mt][t], bl.s, acc[mt], 0, 0, 0);
                }
            }
            int col = nb * 16 + m;
            float ev = e2[col];
            #pragma unroll
            for (int mt = 0; mt < 4; ++mt)
                #pragma unroll
                for (int r = 0; r < 4; ++r) {
                    float s = fmaf(-2.0f, acc[mt][r], ev);
                    if (s < m1[mt][r]) { m2[mt][r] = m1[mt][r]; m1[mt][r] = s; i1[mt][r] = col; }
                    else if (s < m2[mt][r]) { m2[mt][r] = s; }
                }
        }
        __syncthreads();   // staging c+1 complete; buf (c-1 slot) reusable
    }

    // ---------- merge across the 16 lanes of each quad ----------
    #pragma unroll
    for (int mt = 0; mt < 4; ++mt)
        #pragma unroll
        for (int r = 0; r < 4; ++r) {
            float a1 = m1[mt][r], a2 = m2[mt][r];
            int ai = i1[mt][r];
            #pragma unroll
            for (int off = 1; off < 16; off <<= 1) {
                float o1 = __shfl_xor(a1, off, 64);
                float o2 = __shfl_xor(a2, off, 64);
                int oi = __shfl_xor(ai, off, 64);
                float hi = fmaxf(a1, o1);
                float n2 = fminf(fminf(a2, o2), hi);
                bool take = (o1 < a1) || (o1 == a1 && oi < ai);  // first-index ties
                a1 = fminf(a1, o1);
                ai = take ? oi : ai;
                a2 = n2;
            }
            m1[mt][r] = a1; m2[mt][r] = a2; i1[mt][r] = ai;
        }

    // ---------- write idx, LDS-aggregated histogram, refine list ----------
    int* hist = (int*)&Bs[0][0];
    for (int i = tid; i < KCODE; i += 256) hist[i] = 0;
    __syncthreads();
    if (m == 0) {   // 4 representative lanes per wave (one per quad)
        #pragma unroll
        for (int mt = 0; mt < 4; ++mt)
            #pragma unroll
            for (int r = 0; r < 4; ++r) {
                int row = rw + mt * 16 + q * 4 + r;
                int bi = i1[mt][r];
                idx[row] = bi;
                atomicAdd(&hist[bi], 1);
                if (!(m2[mt][r] - m1[mt][r] > MARGIN)) {
                    int pos = atomicAdd(refine_cnt, 1);
                    refine_rows[pos] = row;
                }
            }
    }
    __syncthreads();
    for (int i = tid; i < KCODE; i += 256) {
        int h = hist[i];
        if (h) atomicAdd(&counts[i], h);
    }
}

// ============================================================
// fp64 exact re-resolution of ambiguous rows + histogram delta
__global__ void vq_refine(const float* __restrict__ x, const float* __restrict__ E,
                          const int* __restrict__ refine_rows,
                          const int* __restrict__ refine_cnt, int* __restrict__ idx,
                          int* __restrict__ counts) {
    __shared__ float xs[DIMD];
    __shared__ double rm[256];
    __shared__ int ri[256];
    int cnt = *refine_cnt;
    for (int wli = blockIdx.x; wli < cnt; wli += gridDim.x) {
        int n = refine_rows[wli];
        __syncthreads();
        if (threadIdx.x < DIMD) xs[threadIdx.x] = x[(size_t)n * DIMD + threadIdx.x];
        __syncthreads();
        double best = DBL_MAX;
        int bi = 0;
        for (int k = threadIdx.x; k < KCODE; k += 256) {
            double s = 0.0;
            for (int d = 0; d < DIMD; ++d) {
                double diff = (double)xs[d] - (double)E[(size_t)d * KCODE + k];
                s = fma(diff, diff, s);
            }
            if (s < best) { best = s; bi = k; }
        }
        rm[threadIdx.x] = best; ri[threadIdx.x] = bi;
        __syncthreads();
        for (int off = 128; off > 0; off >>= 1) {
            if (threadIdx.x < off) {
                double o = rm[threadIdx.x + off];
                int oi = ri[threadIdx.x + off];
                if (o < rm[threadIdx.x] ||
                    (o == rm[threadIdx.x] && oi < ri[threadIdx.x])) {
                    rm[threadIdx.x] = o; ri[threadIdx.x] = oi;
                }
            }
            __syncthreads();
        }
        if (threadIdx.x == 0) {
            int newk = ri[0], oldk = idx[n];
            if (newk != oldk) {
                idx[n] = newk;
                atomicSub(&counts[oldk], 1);
                atomicAdd(&counts[newk], 1);
            }
        }
    }
}

// ============================================================
__global__ void vq_scan(const int* __restrict__ counts, int* __restrict__ offsets,
                        int* __restrict__ cursor) {
    __shared__ int s[KCODE];
    int t = threadIdx.x;
    int c = counts[t];
    s[t] = c;
    __syncthreads();
    for (int off = 1; off < KCODE; off <<= 1) {
        int v = (t >= off) ? s[t - off] : 0;
        __syncthreads();
        s[t] += v;
        __syncthreads();
    }
    int excl = s[t] - c;
    offsets[t] = excl;
    cursor[t] = excl;
}

// LDS-aggregated bucket fill (kills same-address global atomic chains)
__global__ void vq_fill(const int* __restrict__ idx, int* __restrict__ cursor,
                        int* __restrict__ rowlist) {
    __shared__ int hcnt[KCODE];
    __shared__ int hbase[KCODE];
    int tid = threadIdx.x;
    for (int i = tid; i < KCODE; i += 256) hcnt[i] = 0;
    __syncthreads();
    int n = blockIdx.x * 256 + tid;
    int k = idx[n];
    int lrank = atomicAdd(&hcnt[k], 1);
    __syncthreads();
    for (int i = tid; i < KCODE; i += 256) {
        int h = hcnt[i];
        if (h) hbase[i] = atomicAdd(&cursor[i], h);
    }
    __syncthreads();
    rowlist[hbase[k] + lrank] = n;
}

// Balanced segment-sum: each block scans 128 rowlist entries (sorted by code),
// accumulates per-thread-d partials, flushes at code boundaries via atomics.
__global__ void vq_chunksum(const float* __restrict__ x,
                            const int* __restrict__ rowlist,
                            const int* __restrict__ idx,
                            float* __restrict__ sums) {
    __shared__ int rl[128];
    __shared__ int kk[128];
    int tid = threadIdx.x;   // 128 threads, tid == d
    int base = blockIdx.x * 128;
    int r = rowlist[base + tid];
    rl[tid] = r;
    kk[tid] = idx[r];
    __syncthreads();
    float s = 0.f;
    int kprev = kk[0];
    #pragma unroll 4
    for (int j = 0; j < 128; ++j) {
        int kj = kk[j];
        if (kj != kprev) {
            atomicAdd(&sums[(size_t)kprev * DIMD + tid], s);
            s = 0.f;
            kprev = kj;
        }
        s += x[(size_t)rl[j] * DIMD + tid];
    }
    atomicAdd(&sums[(size_t)kprev * DIMD + tid], s);
}

// EMA outputs from sums + counts
__global__ void vq_finalize_emb(const int* __restrict__ counts,
                                const float* __restrict__ sums,
                                const float* __restrict__ emc,
                                const float* __restrict__ es,
                                float* __restrict__ out) {
    int gid = blockIdx.x * 256 + threadIdx.x;   // 131072
    int k = gid & (KCODE - 1), d = gid >> 10;
    float cnt = (float)counts[k];
    float ecn = fmaf(0.85f, cnt, 0.15f * emc[k]);
    float esn = fmaf(0.85f, sums[(size_t)k * DIMD + d], 0.15f * es[(size_t)d * KCODE + k]);
    out[OUT_ES + (size_t)d * KCODE + k] = esn;
    out[OUT_EMB + (size_t)d * KCODE + k] = esn / fmaxf(ecn, 1e-5f);
    if (d == 0) out[OUT_CNT + k] = ecn;
}

// q_st = x + (quantized - x) (replicating reference fp32 rounding) + loss
__global__ void vq_quantize_loss(const float* __restrict__ x,
                                 const float* __restrict__ ET,
                                 const int* __restrict__ idx,
                                 float* __restrict__ out,
                                 double* __restrict__ loss) {
    size_t gid = (size_t)blockIdx.x * 256 + threadIdx.x;
    size_t base = gid * 4;
    int n = (int)(base >> 7);
    int d = (int)(base & 127);
    int k = idx[n];
    float4 xv = *(const float4*)(x + base);
    float4 qv = *(const float4*)(ET + (size_t)k * DIMD + d);
    float t0 = qv.x - xv.x, t1 = qv.y - xv.y, t2 = qv.z - xv.z, t3 = qv.w - xv.w;
    float4 o;
    o.x = xv.x + t0; o.y = xv.y + t1; o.z = xv.z + t2; o.w = xv.w + t3;
    *(float4*)(out + OUT_QST + base) = o;
    float partial = t0 * t0 + t1 * t1 + t2 * t2 + t3 * t3;
    #pragma unroll
    for (int off = 32; off > 0; off >>= 1)
        partial += __shfl_down(partial, off);
    __shared__ float wsum[4];
    int wave = threadIdx.x >> 6;
    if ((threadIdx.x & 63) == 0) wsum[wave] = partial;
    __syncthreads();
    if (threadIdx.x == 0)
        atomicAdd(loss, (double)(wsum[0] + wsum[1] + wsum[2] + wsum[3]));
}

__global__ void vq_finalize_loss(const double* __restrict__ loss, float* __restrict__ out) {
    out[OUT_LOSS] = (float)(*loss / ((double)NROWS * (double)DIMD));  // BETA = 1
}

// ============================================================
extern "C" void kernel_launch(void* const* d_in, const int* in_sizes, int n_in,
                              void* d_out, int out_size, void* d_ws, size_t ws_size,
                              hipStream_t stream) {
    const float* x   = (const float*)d_in[0];
    const float* E   = (const float*)d_in[1];
    const float* emc = (const float*)d_in[2];
    const float* es  = (const float*)d_in[3];
    float* out = (float*)d_out;
    char* ws = (char*)d_ws;

    int*    refine_cnt  = (int*)(ws + WS_REFINE_CNT);
    double* loss        = (double*)(ws + WS_LOSS);
    int*    counts      = (int*)(ws + WS_COUNTS);
    float*  sums        = (float*)(ws + WS_SUMS);
    int*    offsets     = (int*)(ws + WS_OFFSETS);
    int*    cursor      = (int*)(ws + WS_CURSOR);
    float*  e2          = (float*)(ws + WS_E2);
    float*  ET          = (float*)(ws + WS_ET);
    uint4*  Bhi         = (uint4*)(ws + WS_BHI);
    uint4*  Blo         = (uint4*)(ws + WS_BLO);
    int*    idx         = (int*)(ws + WS_IDX);
    int*    rowlist     = (int*)(ws + WS_ROWLIST);
    int*    refine_rows = (int*)(ws + WS_REFINE);

    (void)offsets;  // kept for layout clarity (scan writes offsets+cursor)

    // zero: refine counter, loss, counts, sums
    hipMemsetAsync(ws, 0, WS_ZERO_BYTES, stream);

    vq_prep_e2<<<4, 256, 0, stream>>>(E, e2);
    vq_transpose<<<dim3(KCODE / 32, DIMD / 32), dim3(32, 8), 0, stream>>>(E, ET);
    vq_prep_bfrag<<<64, 256, 0, stream>>>(E, Bhi, Blo);
    vq_argmin_mfma<<<NROWS / 256, 256, 0, stream>>>(x, Bhi, Blo, e2, idx, counts,
                                                    refine_rows, refine_cnt);
    vq_refine<<<256, 256, 0, stream>>>(x, E, refine_rows, refine_cnt, idx, counts);
    vq_scan<<<1, KCODE, 0, stream>>>(counts, offsets, cursor);
    vq_fill<<<NROWS / 256, 256, 0, stream>>>(idx, cursor, rowlist);
    vq_chunksum<<<NROWS / 128, 128, 0, stream>>>(x, rowlist, idx, sums);
    vq_finalize_emb<<<(DIMD * KCODE) / 256, 256, 0, stream>>>(counts, sums, emc, es, out);
    vq_quantize_loss<<<(NROWS * (size_t)DIMD) / (256 * 4), 256, 0, stream>>>(x, ET, idx, out, loss);
    vq_finalize_loss<<<1, 1, 0, stream>>>(loss, out);
}

// Round 3
// 412.606 us; speedup vs baseline: 3.1125x; 1.4126x over previous
//
#include <hip/hip_runtime.h>
#include <cfloat>
#include <cstdint>

// Problem constants
#define NROWS 131072
#define DIMD  128
#define KCODE 1024
#define MARGIN 0.02f   // fast-path gap below which we re-resolve argmin in fp64

typedef __attribute__((ext_vector_type(8))) short short8;  // 8 bf16 = 4 VGPRs
typedef __attribute__((ext_vector_type(4))) float f32x4;

union U4S8 { uint4 u; short8 s; };

// ---- workspace layout (bytes); total ~3.23 MB ----
#define WS_REFINE_CNT 0         // int
#define WS_LOSS       8         // double (unused slot kept for layout stability)
#define WS_COUNTS     16        // int[1024]
#define WS_SUMS       4608      // float[K*D] = 512 KB (layout [k][d])
#define WS_ZERO_BYTES 528896    // memset [0, WS_ZERO_BYTES)
#define WS_OFFSETS    528896    // int[1024]
#define WS_CURSOR     532992    // int[1024]
#define WS_E2         537088    // float[1024]
#define WS_ET         541184    // float[K*D] (ET[k][d])
#define WS_BHI        1065472   // uint4[16384] = 256 KB (B hi fragments)
#define WS_BLO        1327616   // uint4[16384]
#define WS_IDX        1589760   // int[N]
#define WS_ROWLIST    2114048   // int[N]
#define WS_REFINE     2638336   // int[N]
#define WS_PARTIALS   3162624   // float[16384] per-block loss partials
// end: 3228160 bytes

// ---- output offsets (in floats), reference return order ----
#define OUT_QST  ((size_t)0)
#define OUT_EMB  ((size_t)NROWS * DIMD)
#define OUT_CNT  (OUT_EMB + (size_t)DIMD * KCODE)
#define OUT_ES   (OUT_CNT + KCODE)
#define OUT_LOSS (OUT_ES + (size_t)DIMD * KCODE)

// bf16 round-to-nearest-even of a float, as uint16 payload
__device__ __forceinline__ unsigned bf16rne(float f) {
    union { float f; unsigned u; } c; c.f = f;
    return (c.u + 0x7fffu + ((c.u >> 16) & 1u)) >> 16;
}
__device__ __forceinline__ float bf16back(unsigned h) {
    union { unsigned u; float f; } c; c.u = h << 16;
    return c.f;
}

// ============================================================
// e2[k] = sum_d E[d][k]^2   (coalesced over k)
__global__ void vq_prep_e2(const float* __restrict__ E, float* __restrict__ e2) {
    int k = blockIdx.x * 256 + threadIdx.x;
    if (k >= KCODE) return;
    float s = 0.f;
    for (int d = 0; d < DIMD; ++d) {
        float v = E[(size_t)d * KCODE + k];
        s = fmaf(v, v, s);
    }
    e2[k] = s;
}

// ET[k][d] = E[d][k]  (LDS-tiled transpose)
__global__ void vq_transpose(const float* __restrict__ E, float* __restrict__ ET) {
    __shared__ float tile[32][33];
    int kb = blockIdx.x * 32, db = blockIdx.y * 32;
    int tx = threadIdx.x, ty = threadIdx.y;  // 32 x 8
    #pragma unroll
    for (int j = 0; j < 32; j += 8)
        tile[ty + j][tx] = E[(size_t)(db + ty + j) * KCODE + kb + tx];
    __syncthreads();
    #pragma unroll
    for (int j = 0; j < 32; j += 8)
        ET[(size_t)(kb + ty + j) * DIMD + db + tx] = tile[tx][ty + j];
}

// Pack E into MFMA B-fragment order, split hi/lo bf16.
// Fragment fi = (NB*4 + t)*64 + lane; lane holds B[k = t*32 + (lane>>4)*8 + j]
// [n = NB*16 + (lane&15)], j = 0..7, value = E[k][n] (k is the d-dimension).
__global__ void vq_prep_bfrag(const float* __restrict__ E,
                              uint4* __restrict__ Bhi, uint4* __restrict__ Blo) {
    int gid = blockIdx.x * 256 + threadIdx.x;   // 0..16383 == fi
    int l = gid & 63;
    int t = (gid >> 6) & 3;
    int NB = gid >> 8;
    int n = NB * 16 + (l & 15);
    int k0 = t * 32 + (l >> 4) * 8;
    unsigned hu[8], lu[8];
    #pragma unroll
    for (int j = 0; j < 8; ++j) {
        float v = E[(size_t)(k0 + j) * KCODE + n];
        unsigned h = bf16rne(v);
        hu[j] = h;
        lu[j] = bf16rne(v - bf16back(h));
    }
    Bhi[gid] = make_uint4(hu[0] | (hu[1] << 16), hu[2] | (hu[3] << 16),
                          hu[4] | (hu[5] << 16), hu[6] | (hu[7] << 16));
    Blo[gid] = make_uint4(lu[0] | (lu[1] << 16), lu[2] | (lu[3] << 16),
                          lu[4] | (lu[5] << 16), lu[6] | (lu[7] << 16));
}

// ============================================================
// async global->LDS 16B copy
__device__ __forceinline__ void async16(const uint4* g, uint4* l) {
    __builtin_amdgcn_global_load_lds(
        (const __attribute__((address_space(1))) void*)g,
        (__attribute__((address_space(3))) void*)l, 16, 0, 0);
}

// Stage one 64-code chunk (hi 16KB + lo 16KB) into LDS, wave-partitioned.
__device__ __forceinline__ void stage_chunk(const uint4* __restrict__ Bhi,
                                            const uint4* __restrict__ Blo,
                                            int c, uint4* buf, int w, int l) {
    const uint4* src = (w < 2) ? (Bhi + c * 1024 + w * 512 + l)
                               : (Blo + c * 1024 + (w - 2) * 512 + l);
    uint4* dst = buf + w * 512 + l;
    #pragma unroll
    for (int j = 0; j < 8; ++j)
        async16(src + j * 64, dst + j * 64);
}

// Main kernel: per-row argmin_k ( ||e_k||^2 - 2 x.e_k ) via bf16 hi/lo split
// MFMA (3 passes: hh + lh + hl; residual ~1e-3 << MARGIN). 256 rows/block,
// 4 waves x 64 rows (4 m-tiles of 16). B double-buffered in LDS via
// global_load_lds; A fragments built in-register via per-wave swizzled LDS
// scratch. Running (min1,min2,idx) per row in MFMA C-layout, shfl_xor merge.
__global__ __launch_bounds__(256, 2) void vq_argmin_mfma(
        const float* __restrict__ x, const uint4* __restrict__ Bhi,
        const uint4* __restrict__ Blo, const float* __restrict__ e2,
        int* __restrict__ idx, int* __restrict__ counts,
        int* __restrict__ refine_rows, int* __restrict__ refine_cnt) {

    __shared__ uint4 Bs[2][2048];   // 2 x 32 KB

    const int tid = threadIdx.x;
    const int w = tid >> 6, l = tid & 63;
    const int m = l & 15, q = l >> 4;
    const int row0 = blockIdx.x * 256;
    const int rw = row0 + w * 64;

    // ---------- A-phase: build hi/lo A-fragments in registers ----------
    short8 ah[4][4], al[4][4];      // [m-tile][k-tile]
    float4* sc4 = ((float4*)&Bs[1][0]) + w * 512;   // 8 KB private scratch/wave

    #pragma unroll
    for (int mt = 0; mt < 4; ++mt) {
        int rm = rw + mt * 16;
        #pragma unroll
        for (int i = 0; i < 8; ++i) {
            int f = i * 64 + l, r = f >> 5, g = f & 31;
            float4 v = ((const float4*)x)[(size_t)(rm + r) * 32 + g];
            sc4[r * 32 + (g ^ ((r & 7) << 2))] = v;   // XOR swizzle vs banks
        }
        __builtin_amdgcn_s_waitcnt(0);   // in-wave LDS write->read ordering
        int sw = (m & 7) << 2;
        #pragma unroll
        for (int t = 0; t < 4; ++t) {
            int g0 = t * 8 + q * 2;
            float4 va = sc4[m * 32 + (g0 ^ sw)];
            float4 vb = sc4[m * 32 + ((g0 + 1) ^ sw)];
            float f8[8] = {va.x, va.y, va.z, va.w, vb.x, vb.y, vb.z, vb.w};
            unsigned hu[8], lu[8];
            #pragma unroll
            for (int j = 0; j < 8; ++j) {
                unsigned h = bf16rne(f8[j]);
                hu[j] = h;
                lu[j] = bf16rne(f8[j] - bf16back(h));
            }
            U4S8 ch, cl;
            ch.u = make_uint4(hu[0] | (hu[1] << 16), hu[2] | (hu[3] << 16),
                              hu[4] | (hu[5] << 16), hu[6] | (hu[7] << 16));
            cl.u = make_uint4(lu[0] | (lu[1] << 16), lu[2] | (lu[3] << 16),
                              lu[4] | (lu[5] << 16), lu[6] | (lu[7] << 16));
            ah[mt][t] = ch.s;
            al[mt][t] = cl.s;
        }
    }

    float m1[4][4], m2[4][4];
    int i1[4][4];
    #pragma unroll
    for (int a = 0; a < 4; ++a)
        #pragma unroll
        for (int r = 0; r < 4; ++r) { m1[a][r] = FLT_MAX; m2[a][r] = FLT_MAX; i1[a][r] = 0; }

    // ---------- K-loop over 16 chunks of 64 codes ----------
    stage_chunk(Bhi, Blo, 0, &Bs[0][0], w, l);
    __syncthreads();   // also covers: all waves done with scratch (Bs[1])

    for (int c = 0; c < 16; ++c) {
        if (c < 15) stage_chunk(Bhi, Blo, c + 1, &Bs[(c + 1) & 1][0], w, l);
        uint4* buf = &Bs[c & 1][0];
        #pragma unroll
        for (int b = 0; b < 4; ++b) {
            int nb = c * 4 + b;
            f32x4 acc[4];
            #pragma unroll
            for (int mt = 0; mt < 4; ++mt) acc[mt] = (f32x4){0.f, 0.f, 0.f, 0.f};
            #pragma unroll
            for (int t = 0; t < 4; ++t) {
                U4S8 bh, bl;
                bh.u = buf[(b * 4 + t) * 64 + l];
                bl.u = buf[1024 + (b * 4 + t) * 64 + l];
                #pragma unroll
                for (int mt = 0; mt < 4; ++mt) {
                    acc[mt] = __builtin_amdgcn_mfma_f32_16x16x32_bf16(ah[mt][t], bh.s, acc[mt], 0, 0, 0);
                    acc[mt] = __builtin_amdgcn_mfma_f32_16x16x32_bf16(al[mt][t], bh.s, acc[mt], 0, 0, 0);
                    acc[mt] = __builtin_amdgcn_mfma_f32_16x16x32_bf16(ah[mt][t], bl.s, acc[mt], 0, 0, 0);
                }
            }
            int col = nb * 16 + m;
            float ev = e2[col];
            #pragma unroll
            for (int mt = 0; mt < 4; ++mt)
                #pragma unroll
                for (int r = 0; r < 4; ++r) {
                    float s = fmaf(-2.0f, acc[mt][r], ev);
                    if (s < m1[mt][r]) { m2[mt][r] = m1[mt][r]; m1[mt][r] = s; i1[mt][r] = col; }
                    else if (s < m2[mt][r]) { m2[mt][r] = s; }
                }
        }
        __syncthreads();   // staging c+1 complete; buf (c-1 slot) reusable
    }

    // ---------- merge across the 16 lanes of each quad ----------
    #pragma unroll
    for (int mt = 0; mt < 4; ++mt)
        #pragma unroll
        for (int r = 0; r < 4; ++r) {
            float a1 = m1[mt][r], a2 = m2[mt][r];
            int ai = i1[mt][r];
            #pragma unroll
            for (int off = 1; off < 16; off <<= 1) {
                float o1 = __shfl_xor(a1, off, 64);
                float o2 = __shfl_xor(a2, off, 64);
                int oi = __shfl_xor(ai, off, 64);
                float hi = fmaxf(a1, o1);
                float n2 = fminf(fminf(a2, o2), hi);
                bool take = (o1 < a1) || (o1 == a1 && oi < ai);  // first-index ties
                a1 = fminf(a1, o1);
                ai = take ? oi : ai;
                a2 = n2;
            }
            m1[mt][r] = a1; m2[mt][r] = a2; i1[mt][r] = ai;
        }

    // ---------- write idx, LDS-aggregated histogram, refine list ----------
    int* hist = (int*)&Bs[0][0];
    for (int i = tid; i < KCODE; i += 256) hist[i] = 0;
    __syncthreads();
    if (m == 0) {   // 4 representative lanes per wave (one per quad)
        #pragma unroll
        for (int mt = 0; mt < 4; ++mt)
            #pragma unroll
            for (int r = 0; r < 4; ++r) {
                int row = rw + mt * 16 + q * 4 + r;
                int bi = i1[mt][r];
                idx[row] = bi;
                atomicAdd(&hist[bi], 1);
                if (!(m2[mt][r] - m1[mt][r] > MARGIN)) {
                    int pos = atomicAdd(refine_cnt, 1);
                    refine_rows[pos] = row;
                }
            }
    }
    __syncthreads();
    for (int i = tid; i < KCODE; i += 256) {
        int h = hist[i];
        if (h) atomicAdd(&counts[i], h);
    }
}

// ============================================================
// fp64 exact re-resolution of ambiguous rows + histogram delta
__global__ void vq_refine(const float* __restrict__ x, const float* __restrict__ E,
                          const int* __restrict__ refine_rows,
                          const int* __restrict__ refine_cnt, int* __restrict__ idx,
                          int* __restrict__ counts) {
    __shared__ float xs[DIMD];
    __shared__ double rm[256];
    __shared__ int ri[256];
    int cnt = *refine_cnt;
    for (int wli = blockIdx.x; wli < cnt; wli += gridDim.x) {
        int n = refine_rows[wli];
        __syncthreads();
        if (threadIdx.x < DIMD) xs[threadIdx.x] = x[(size_t)n * DIMD + threadIdx.x];
        __syncthreads();
        double best = DBL_MAX;
        int bi = 0;
        for (int k = threadIdx.x; k < KCODE; k += 256) {
            double s = 0.0;
            for (int d = 0; d < DIMD; ++d) {
                double diff = (double)xs[d] - (double)E[(size_t)d * KCODE + k];
                s = fma(diff, diff, s);
            }
            if (s < best) { best = s; bi = k; }
        }
        rm[threadIdx.x] = best; ri[threadIdx.x] = bi;
        __syncthreads();
        for (int off = 128; off > 0; off >>= 1) {
            if (threadIdx.x < off) {
                double o = rm[threadIdx.x + off];
                int oi = ri[threadIdx.x + off];
                if (o < rm[threadIdx.x] ||
                    (o == rm[threadIdx.x] && oi < ri[threadIdx.x])) {
                    rm[threadIdx.x] = o; ri[threadIdx.x] = oi;
                }
            }
            __syncthreads();
        }
        if (threadIdx.x == 0) {
            int newk = ri[0], oldk = idx[n];
            if (newk != oldk) {
                idx[n] = newk;
                atomicSub(&counts[oldk], 1);
                atomicAdd(&counts[newk], 1);
            }
        }
    }
}

// ============================================================
__global__ void vq_scan(const int* __restrict__ counts, int* __restrict__ offsets,
                        int* __restrict__ cursor) {
    __shared__ int s[KCODE];
    int t = threadIdx.x;
    int c = counts[t];
    s[t] = c;
    __syncthreads();
    for (int off = 1; off < KCODE; off <<= 1) {
        int v = (t >= off) ? s[t - off] : 0;
        __syncthreads();
        s[t] += v;
        __syncthreads();
    }
    int excl = s[t] - c;
    offsets[t] = excl;
    cursor[t] = excl;
}

// LDS-aggregated bucket fill (kills same-address global atomic chains)
__global__ void vq_fill(const int* __restrict__ idx, int* __restrict__ cursor,
                        int* __restrict__ rowlist) {
    __shared__ int hcnt[KCODE];
    __shared__ int hbase[KCODE];
    int tid = threadIdx.x;
    for (int i = tid; i < KCODE; i += 256) hcnt[i] = 0;
    __syncthreads();
    int n = blockIdx.x * 256 + tid;
    int k = idx[n];
    int lrank = atomicAdd(&hcnt[k], 1);
    __syncthreads();
    for (int i = tid; i < KCODE; i += 256) {
        int h = hcnt[i];
        if (h) hbase[i] = atomicAdd(&cursor[i], h);
    }
    __syncthreads();
    rowlist[hbase[k] + lrank] = n;
}

// Balanced segment-sum: each block scans 128 rowlist entries (sorted by code),
// accumulates per-thread-d partials, flushes at code boundaries via atomics.
__global__ void vq_chunksum(const float* __restrict__ x,
                            const int* __restrict__ rowlist,
                            const int* __restrict__ idx,
                            float* __restrict__ sums) {
    __shared__ int rl[128];
    __shared__ int kk[128];
    int tid = threadIdx.x;   // 128 threads, tid == d
    int base = blockIdx.x * 128;
    int r = rowlist[base + tid];
    rl[tid] = r;
    kk[tid] = idx[r];
    __syncthreads();
    float s = 0.f;
    int kprev = kk[0];
    #pragma unroll 4
    for (int j = 0; j < 128; ++j) {
        int kj = kk[j];
        if (kj != kprev) {
            atomicAdd(&sums[(size_t)kprev * DIMD + tid], s);
            s = 0.f;
            kprev = kj;
        }
        s += x[(size_t)rl[j] * DIMD + tid];
    }
    atomicAdd(&sums[(size_t)kprev * DIMD + tid], s);
}

// EMA outputs from sums + counts
__global__ void vq_finalize_emb(const int* __restrict__ counts,
                                const float* __restrict__ sums,
                                const float* __restrict__ emc,
                                const float* __restrict__ es,
                                float* __restrict__ out) {
    int gid = blockIdx.x * 256 + threadIdx.x;   // 131072
    int k = gid & (KCODE - 1), d = gid >> 10;
    float cnt = (float)counts[k];
    float ecn = fmaf(0.85f, cnt, 0.15f * emc[k]);
    float esn = fmaf(0.85f, sums[(size_t)k * DIMD + d], 0.15f * es[(size_t)d * KCODE + k]);
    out[OUT_ES + (size_t)d * KCODE + k] = esn;
    out[OUT_EMB + (size_t)d * KCODE + k] = esn / fmaxf(ecn, 1e-5f);
    if (d == 0) out[OUT_CNT + k] = ecn;
}

// q_st = x + (quantized - x) (replicating reference fp32 rounding) + loss
// partials: one fp32 per block (distributed stores — no same-address atomics)
__global__ void vq_quantize_loss(const float* __restrict__ x,
                                 const float* __restrict__ ET,
                                 const int* __restrict__ idx,
                                 float* __restrict__ out,
                                 float* __restrict__ partials) {
    size_t gid = (size_t)blockIdx.x * 256 + threadIdx.x;
    size_t base = gid * 4;
    int n = (int)(base >> 7);
    int d = (int)(base & 127);
    int k = idx[n];
    float4 xv = *(const float4*)(x + base);
    float4 qv = *(const float4*)(ET + (size_t)k * DIMD + d);
    float t0 = qv.x - xv.x, t1 = qv.y - xv.y, t2 = qv.z - xv.z, t3 = qv.w - xv.w;
    float4 o;
    o.x = xv.x + t0; o.y = xv.y + t1; o.z = xv.z + t2; o.w = xv.w + t3;
    *(float4*)(out + OUT_QST + base) = o;
    float partial = t0 * t0 + t1 * t1 + t2 * t2 + t3 * t3;
    #pragma unroll
    for (int off = 32; off > 0; off >>= 1)
        partial += __shfl_down(partial, off);
    __shared__ float wsum[4];
    int wave = threadIdx.x >> 6;
    if ((threadIdx.x & 63) == 0) wsum[wave] = partial;
    __syncthreads();
    if (threadIdx.x == 0)
        partials[blockIdx.x] = wsum[0] + wsum[1] + wsum[2] + wsum[3];
}

// Single-block tree reduction of the 16384 per-block partials -> loss scalar
__global__ void vq_finalize_loss(const float* __restrict__ partials,
                                 float* __restrict__ out) {
    float s = 0.f;
    for (int i = threadIdx.x; i < 16384; i += 256)
        s += partials[i];
    #pragma unroll
    for (int off = 32; off > 0; off >>= 1)
        s += __shfl_down(s, off);
    __shared__ float wsum[4];
    int wave = threadIdx.x >> 6;
    if ((threadIdx.x & 63) == 0) wsum[wave] = s;
    __syncthreads();
    if (threadIdx.x == 0) {
        float tot = wsum[0] + wsum[1] + wsum[2] + wsum[3];
        out[OUT_LOSS] = tot / ((float)NROWS * (float)DIMD);  // BETA = 1
    }
}

// ============================================================
extern "C" void kernel_launch(void* const* d_in, const int* in_sizes, int n_in,
                              void* d_out, int out_size, void* d_ws, size_t ws_size,
                              hipStream_t stream) {
    const float* x   = (const float*)d_in[0];
    const float* E   = (const float*)d_in[1];
    const float* emc = (const float*)d_in[2];
    const float* es  = (const float*)d_in[3];
    float* out = (float*)d_out;
    char* ws = (char*)d_ws;

    int*    refine_cnt  = (int*)(ws + WS_REFINE_CNT);
    int*    counts      = (int*)(ws + WS_COUNTS);
    float*  sums        = (float*)(ws + WS_SUMS);
    int*    offsets     = (int*)(ws + WS_OFFSETS);
    int*    cursor      = (int*)(ws + WS_CURSOR);
    float*  e2          = (float*)(ws + WS_E2);
    float*  ET          = (float*)(ws + WS_ET);
    uint4*  Bhi         = (uint4*)(ws + WS_BHI);
    uint4*  Blo         = (uint4*)(ws + WS_BLO);
    int*    idx         = (int*)(ws + WS_IDX);
    int*    rowlist     = (int*)(ws + WS_ROWLIST);
    int*    refine_rows = (int*)(ws + WS_REFINE);
    float*  partials    = (float*)(ws + WS_PARTIALS);

    // zero: refine counter, counts, sums
    hipMemsetAsync(ws, 0, WS_ZERO_BYTES, stream);

    vq_prep_e2<<<4, 256, 0, stream>>>(E, e2);
    vq_transpose<<<dim3(KCODE / 32, DIMD / 32), dim3(32, 8), 0, stream>>>(E, ET);
    vq_prep_bfrag<<<64, 256, 0, stream>>>(E, Bhi, Blo);
    vq_argmin_mfma<<<NROWS / 256, 256, 0, stream>>>(x, Bhi, Blo, e2, idx, counts,
                                                    refine_rows, refine_cnt);
    vq_refine<<<256, 256, 0, stream>>>(x, E, refine_rows, refine_cnt, idx, counts);
    vq_scan<<<1, KCODE, 0, stream>>>(counts, offsets, cursor);
    vq_fill<<<NROWS / 256, 256, 0, stream>>>(idx, cursor, rowlist);
    vq_chunksum<<<NROWS / 128, 128, 0, stream>>>(x, rowlist, idx, sums);
    vq_finalize_emb<<<(DIMD * KCODE) / 256, 256, 0, stream>>>(counts, sums, emc, es, out);
    vq_quantize_loss<<<(NROWS * (size_t)DIMD) / (256 * 4), 256, 0, stream>>>(x, ET, idx, out, partials);
    vq_finalize_loss<<<1, 256, 0, stream>>>(partials, out);
}